// Round 6
// baseline (546.565 us; speedup 1.0000x reference)
//
#include <hip/hip_runtime.h>

// Problem constants
constexpr int W   = 240;
constexpr int H   = 128;
constexpr int D   = 48;   // disparity bins
constexpr int G   = 40;   // groups
constexpr int CPG = 8;    // channels per group (320/40)
constexpr int CC  = 12;   // concat channels
constexpr int HW  = H * W;
constexpr int PAD = 48;        // left zero-pad so tgt[w-d] (w<d) reads zeros
constexpr int TROW = PAD + W;  // 288 floats per padded row

constexpr int NGWC = G * H;       // 5120 gwc blocks
constexpr int NCAT = 2 * CC * H;  // 3072 concat blocks (c2 0..23 x h)
// Interleave 5 gwc : 3 cat per group of 8 consecutive blockIdx (5120/3072 = 5/3)
constexpr int NGRID = NGWC + NCAT;  // 8192

// Falsification ledger (vs 85.8us round-0 baseline): cached stores +28 (r3),
// f4-nt-store + nt-load bundle +9.3 (r1), h-pair cross-wave adjacency +3.3
// (r2), h-chunk sequential write order +4.5 (r4), no-LDS/no-barrier convoy
// removal +2.3 (r5). Stores: scalar nt quads (verified best). Loads: cached.
// THIS ROUND isolates OCCUPANCY-for-store-drain on the unchanged round-0
// structure: drop sref (compute lanes read their ref float4 directly from
// global -- coalesced; the 4 waves' repeat reads are L1 hits; HBM bytes
// unchanged), keep only the tgt row in LDS (9.2KB). LDS cap goes 4->8
// blocks/CU; VGPR-capped via __launch_bounds__(256,6) -> ~24 waves/CU
// (1.5x round 0's 16) -> 1.5x overlapped nt-store bursts feeding HBM.
__device__ __forceinline__ void nt_store4(float* p, float4 v) {
  __builtin_nontemporal_store(v.x, p + 0);
  __builtin_nontemporal_store(v.y, p + 1);
  __builtin_nontemporal_store(v.z, p + 2);
  __builtin_nontemporal_store(v.w, p + 3);
}

// ---------------------------------------------------------------------------
// Type A (gwc): one block per (g, h). LDS tgt[8][288 padded] only.
//   lane = w4 (60 active), wave dq -> 12 consecutive d via one aligned
//   16-float register window per channel + static slices; ref float4 read
//   directly from global per channel. mean/8 epilogue.
// Type B (cat): one block per (c2, h). LDS one padded row. Same lane/d
//   mapping; ref half = mask-select, tgt half = window slices. Pure copy.
// ---------------------------------------------------------------------------
__global__ __launch_bounds__(256, 6) void fused_kernel(
    const float* __restrict__ ref, const float* __restrict__ tgt,
    const float* __restrict__ refc, const float* __restrict__ tgtc,
    float* __restrict__ out) {
  __shared__ float stgt[CPG][TROW];  // 9216 B

  const int bid = blockIdx.x;
  const int grp = bid >> 3;
  const int rr  = bid & 7;
  const int tid = threadIdx.x;

  const int lane = tid & 63;
  const int dq   = tid >> 6;   // 0..3 -> d block of 12
  const int w4   = lane;       // active if < 60
  const int d0   = dq * 12;

  if (rr < 5) {
    // ---------------- Type A: groupwise correlation ----------------
    const int aid = grp * 5 + rr;      // 0..5119
    const int g   = aid >> 7;
    const int h   = aid & (H - 1);

    // zero left pads: 8c x 12 float4 = 96 slots
    if (tid < CPG * (PAD / 4)) {
      int c = tid / (PAD / 4);
      int i = tid - c * (PAD / 4);
      *(float4*)&stgt[c][i * 4] = make_float4(0.f, 0.f, 0.f, 0.f);
    }
    const size_t rowbase = (size_t)(g * CPG) * HW + (size_t)h * W;
    // stage tgt only: 480 slots (8c x 60x4)
    for (int q = tid; q < CPG * (W / 4); q += 256) {
      int c  = q / (W / 4);
      int x4 = q - c * (W / 4);
      float4 tv = *(const float4*)&tgt[rowbase + (size_t)c * HW + x4 * 4];
      *(float4*)&stgt[c][PAD + x4 * 4] = tv;
    }
    __syncthreads();
    if (w4 >= W / 4) return;

    float4 acc[12];
#pragma unroll
    for (int j = 0; j < 12; ++j) acc[j] = make_float4(0.f, 0.f, 0.f, 0.f);

    const int base = 4 * w4 - d0 - 12;   // aligned (d0 % 4 == 0)
#pragma unroll
    for (int c = 0; c < CPG; ++c) {
      // ref float4 straight from global: coalesced per wave; waves 1..3
      // repeat wave 0's line -> L1 hits. Saves sref staging + LDS.
      float4 r = *(const float4*)&ref[rowbase + (size_t)c * HW + 4 * w4];
      const float4* tp = (const float4*)&stgt[c][PAD + base];
      float tt[16];
      *(float4*)&tt[0]  = tp[0];
      *(float4*)&tt[4]  = tp[1];
      *(float4*)&tt[8]  = tp[2];
      *(float4*)&tt[12] = tp[3];
#pragma unroll
      for (int j = 0; j < 12; ++j) {   // d = d0 + j; window = tt[12-j .. 15-j]
        acc[j].x += r.x * tt[12 - j];
        acc[j].y += r.y * tt[13 - j];
        acc[j].z += r.z * tt[14 - j];
        acc[j].w += r.w * tt[15 - j];
      }
    }

    float* op = out + ((size_t)(g * D + d0) * H + h) * W + 4 * w4;
#pragma unroll
    for (int j = 0; j < 12; ++j) {
      nt_store4(op, make_float4(acc[j].x * 0.125f, acc[j].y * 0.125f,
                                acc[j].z * 0.125f, acc[j].w * 0.125f));
      op += HW;
    }
  } else {
    // ---------------- Type B: concat volume ----------------
    const int cid = grp * 3 + (rr - 5);  // 0..3071
    const int c2  = cid >> 7;            // 0..23
    const int h   = cid & (H - 1);
    float* srow = &stgt[0][0];           // TROW floats

    if (tid < PAD / 4)
      *(float4*)&srow[tid * 4] = make_float4(0.f, 0.f, 0.f, 0.f);
    const bool is_ref = (c2 < CC);
    const float* src = is_ref ? (refc + (size_t)c2 * HW + (size_t)h * W)
                              : (tgtc + (size_t)(c2 - CC) * HW + (size_t)h * W);
    if (tid < W / 4)
      *(float4*)&srow[PAD + tid * 4] = *(const float4*)&src[tid * 4];
    __syncthreads();
    if (w4 >= W / 4) return;

    float* op = out + ((size_t)((G + c2) * D + d0) * H + h) * W + 4 * w4;
    if (is_ref) {
      const float4 rv = *(const float4*)&srow[PAD + 4 * w4];
      const int w0 = 4 * w4;
#pragma unroll
      for (int j = 0; j < 12; ++j) {
        const int d = d0 + j;
        float4 v;
        v.x = (w0 + 0 >= d) ? rv.x : 0.f;
        v.y = (w0 + 1 >= d) ? rv.y : 0.f;
        v.z = (w0 + 2 >= d) ? rv.z : 0.f;
        v.w = (w0 + 3 >= d) ? rv.w : 0.f;
        nt_store4(op, v);
        op += HW;
      }
    } else {
      const int base = 4 * w4 - d0 - 12;
      const float4* tp = (const float4*)&srow[PAD + base];
      float tt[16];
      *(float4*)&tt[0]  = tp[0];
      *(float4*)&tt[4]  = tp[1];
      *(float4*)&tt[8]  = tp[2];
      *(float4*)&tt[12] = tp[3];
#pragma unroll
      for (int j = 0; j < 12; ++j) {
        nt_store4(op, make_float4(tt[12 - j], tt[13 - j], tt[14 - j], tt[15 - j]));
        op += HW;
      }
    }
  }
}

extern "C" void kernel_launch(void* const* d_in, const int* in_sizes, int n_in,
                              void* d_out, int out_size, void* d_ws, size_t ws_size,
                              hipStream_t stream) {
  const float* ref_gwc    = (const float*)d_in[0];
  const float* tgt_gwc    = (const float*)d_in[1];
  const float* ref_concat = (const float*)d_in[2];
  const float* tgt_concat = (const float*)d_in[3];
  float* out = (float*)d_out;

  fused_kernel<<<NGRID, 256, 0, stream>>>(ref_gwc, tgt_gwc, ref_concat,
                                          tgt_concat, out);
}

// Round 7
// 72.553 us; speedup vs baseline: 7.5333x; 7.5333x over previous
//
#include <hip/hip_runtime.h>

// Problem constants
constexpr int W   = 240;
constexpr int H   = 128;
constexpr int D   = 48;   // disparity bins
constexpr int G   = 40;   // groups
constexpr int CPG = 8;    // channels per group (320/40)
constexpr int CC  = 12;   // concat channels
constexpr int HW  = H * W;
constexpr int PAD = 48;        // left zero-pad so tgt[w-d] (w<d) reads zeros
constexpr int TROW = PAD + W;  // 288 floats per padded row

constexpr int NGWC = G * H;       // 5120 gwc blocks
constexpr int NCAT = 2 * CC * H;  // 3072 concat blocks (c2 0..23 x h)
// Interleave 5 gwc : 3 cat per group of 8 consecutive blockIdx (5120/3072 = 5/3)
constexpr int NGRID = NGWC + NCAT;  // 8192

// Ledger vs 85.8us round-0 baseline: cached stores +28 (r3, CLEAR);
// forced 40-VGPR spills +460 (r6, CLEAR -- WRITE_SIZE showed 3.35x
// amplification = scratch traffic); h-pair +3.3 (r2), h-chunk order +4.5
// (r4), no-LDS convoy removal +2.3 (r5) -- all ~noise (+/-3%). r1's +9.3
// bundled f4-nt-stores WITH nt-loads; since the 1.5GB/rep poison fill
// evicts L3 anyway, nt loads should have been ~free -> the width component
// was never isolated. THIS ROUND: f4 nt stores (single global_store_dwordx4
// nt per lane per d; full 64B-line coverage -> 1/4 the TCC write-segment
// count of scalar quads), cached loads, round-0 structure otherwise.
typedef float f4 __attribute__((ext_vector_type(4)));

__device__ __forceinline__ void nt_store(float* p, float4 v) {
  f4 t = {v.x, v.y, v.z, v.w};
  __builtin_nontemporal_store(t, (f4*)p);
}

// ---------------------------------------------------------------------------
// Type A (gwc): one block per (g, h). LDS ref[8][240] + tgt[8][288 padded].
//   lane = w4 (60 active), wave dq -> 12 consecutive d via one aligned
//   16-float register window per channel + static slices. mean/8 epilogue.
// Type B (cat): one block per (c2, h). LDS one padded row. Same lane/d
//   mapping; ref half = mask-select, tgt half = window slices. Pure copy.
// ---------------------------------------------------------------------------
__global__ __launch_bounds__(256) void fused_kernel(const float* __restrict__ ref,
                                                    const float* __restrict__ tgt,
                                                    const float* __restrict__ refc,
                                                    const float* __restrict__ tgtc,
                                                    float* __restrict__ out) {
  __shared__ float sref[CPG][W];
  __shared__ float stgt[CPG][TROW];

  const int bid = blockIdx.x;
  const int grp = bid >> 3;
  const int rr  = bid & 7;
  const int tid = threadIdx.x;

  const int lane = tid & 63;
  const int dq   = tid >> 6;   // 0..3 -> d block of 12
  const int w4   = lane;       // active if < 60
  const int d0   = dq * 12;

  if (rr < 5) {
    // ---------------- Type A: groupwise correlation ----------------
    const int aid = grp * 5 + rr;      // 0..5119
    const int g   = aid >> 7;
    const int h   = aid & (H - 1);

    for (int p = tid; p < CPG * (PAD / 4); p += 256) {
      int c = p / (PAD / 4);
      int i = p - c * (PAD / 4);
      *(float4*)&stgt[c][i * 4] = make_float4(0.f, 0.f, 0.f, 0.f);
    }
    const size_t rowbase = (size_t)(g * CPG) * HW + (size_t)h * W;
    for (int q = tid; q < CPG * (W / 4); q += 256) {
      int c  = q / (W / 4);
      int x4 = q - c * (W / 4);
      float4 rv = *(const float4*)&ref[rowbase + (size_t)c * HW + x4 * 4];
      float4 tv = *(const float4*)&tgt[rowbase + (size_t)c * HW + x4 * 4];
      *(float4*)&sref[c][x4 * 4]       = rv;
      *(float4*)&stgt[c][PAD + x4 * 4] = tv;
    }
    __syncthreads();
    if (w4 >= W / 4) return;

    float4 acc[12];
#pragma unroll
    for (int j = 0; j < 12; ++j) acc[j] = make_float4(0.f, 0.f, 0.f, 0.f);

    const int base = 4 * w4 - d0 - 12;   // aligned (d0 % 4 == 0)
#pragma unroll
    for (int c = 0; c < CPG; ++c) {
      float4 r = *(const float4*)&sref[c][4 * w4];
      const float4* tp = (const float4*)&stgt[c][PAD + base];
      float tt[16];
      *(float4*)&tt[0]  = tp[0];
      *(float4*)&tt[4]  = tp[1];
      *(float4*)&tt[8]  = tp[2];
      *(float4*)&tt[12] = tp[3];
#pragma unroll
      for (int j = 0; j < 12; ++j) {   // d = d0 + j; window = tt[12-j .. 15-j]
        acc[j].x += r.x * tt[12 - j];
        acc[j].y += r.y * tt[13 - j];
        acc[j].z += r.z * tt[14 - j];
        acc[j].w += r.w * tt[15 - j];
      }
    }

    float* op = out + ((size_t)(g * D + d0) * H + h) * W + 4 * w4;
#pragma unroll
    for (int j = 0; j < 12; ++j) {
      nt_store(op, make_float4(acc[j].x * 0.125f, acc[j].y * 0.125f,
                               acc[j].z * 0.125f, acc[j].w * 0.125f));
      op += HW;
    }
  } else {
    // ---------------- Type B: concat volume ----------------
    const int cid = grp * 3 + (rr - 5);  // 0..3071
    const int c2  = cid >> 7;            // 0..23
    const int h   = cid & (H - 1);
    float* srow = &stgt[0][0];           // TROW floats

    if (tid < PAD / 4)
      *(float4*)&srow[tid * 4] = make_float4(0.f, 0.f, 0.f, 0.f);
    const bool is_ref = (c2 < CC);
    const float* src = is_ref ? (refc + (size_t)c2 * HW + (size_t)h * W)
                              : (tgtc + (size_t)(c2 - CC) * HW + (size_t)h * W);
    if (tid < W / 4)
      *(float4*)&srow[PAD + tid * 4] = *(const float4*)&src[tid * 4];
    __syncthreads();
    if (w4 >= W / 4) return;

    float* op = out + ((size_t)((G + c2) * D + d0) * H + h) * W + 4 * w4;
    if (is_ref) {
      const float4 rv = *(const float4*)&srow[PAD + 4 * w4];
      const int w0 = 4 * w4;
#pragma unroll
      for (int j = 0; j < 12; ++j) {
        const int d = d0 + j;
        float4 v;
        v.x = (w0 + 0 >= d) ? rv.x : 0.f;
        v.y = (w0 + 1 >= d) ? rv.y : 0.f;
        v.z = (w0 + 2 >= d) ? rv.z : 0.f;
        v.w = (w0 + 3 >= d) ? rv.w : 0.f;
        nt_store(op, v);
        op += HW;
      }
    } else {
      const int base = 4 * w4 - d0 - 12;
      const float4* tp = (const float4*)&srow[PAD + base];
      float tt[16];
      *(float4*)&tt[0]  = tp[0];
      *(float4*)&tt[4]  = tp[1];
      *(float4*)&tt[8]  = tp[2];
      *(float4*)&tt[12] = tp[3];
#pragma unroll
      for (int j = 0; j < 12; ++j) {
        nt_store(op, make_float4(tt[12 - j], tt[13 - j], tt[14 - j], tt[15 - j]));
        op += HW;
      }
    }
  }
}

extern "C" void kernel_launch(void* const* d_in, const int* in_sizes, int n_in,
                              void* d_out, int out_size, void* d_ws, size_t ws_size,
                              hipStream_t stream) {
  const float* ref_gwc    = (const float*)d_in[0];
  const float* tgt_gwc    = (const float*)d_in[1];
  const float* ref_concat = (const float*)d_in[2];
  const float* tgt_concat = (const float*)d_in[3];
  float* out = (float*)d_out;

  fused_kernel<<<NGRID, 256, 0, stream>>>(ref_gwc, tgt_gwc, ref_concat,
                                          tgt_concat, out);
}